// Round 15
// baseline (3950.873 us; speedup 1.0000x reference)
//
#include <hip/hip_runtime.h>

using short8 = __attribute__((ext_vector_type(8))) short;
using f32x4  = __attribute__((ext_vector_type(4))) float;
using uint4v = __attribute__((ext_vector_type(4))) unsigned;

#define NT     512
#define NBATCH 64
#define NN     1024
#define NIN    24
#define ROWS   8                      // batches per group
#define NGRP   8
#define PARSTRIDE (NGRP * ROWS * NN)  // u32 per parity buffer (256 KB)
#define SCOPE_AGENT __HIP_MEMORY_SCOPE_AGENT
#define RETRY_CAP (1 << 17)           // fail loud (absmax), never hang

// ws: [0, 512KB) obs32: 2 parity buffers of {bf16 | epoch16<<16} words.
// Epoch-in-data sync (R13-proven): producers agent-store tagged words;
// consumers bulk-load with sc1, validate all tags, retry. No flags/fences/inv.

__device__ __forceinline__ unsigned short f2bf(float x) {
  union { float f; unsigned u; } v; v.f = x;
  return (unsigned short)((v.u + 0x7FFFu + ((v.u >> 16) & 1u)) >> 16);
}
__device__ __forceinline__ f32x4 MF(short8 a, short8 b, f32x4 c) {
  return __builtin_amdgcn_mfma_f32_16x16x32_bf16(a, b, c, 0, 0, 0);
}

// 32 blocks x 256 thr (4 waves). slot=bid>>2 owns neurons [128*slot,+128);
// wave owns 32 cols (two 16-col sets, wf0/wf1 = 256 VGPR, 1 wave/SIMD).
// Block serves TWO groups: gA=bid&3, gB=gA+4 (8 batches each), phases
// pipelined so each group's publish->consume latency hides under the other
// group's stage+compute. A-tiles: 8 valid rows; lanes lr>=8 broadcast-read
// row lr&7 (free), their outputs discarded.
__global__ __launch_bounds__(256, 1) void rnn_step_all(
    const float* __restrict__ u, const float* __restrict__ r0,
    const float* __restrict__ W, const float* __restrict__ Bm,
    const float* __restrict__ tau, const float* __restrict__ ds,
    float* __restrict__ out, unsigned* __restrict__ obs32)
{
  __shared__ char lds[2 * ROWS * 2048];   // two 16 KB staged tiles (gA, gB)

  const int tid  = threadIdx.x;
  const int wave = tid >> 6;
  const int lane = tid & 63;
  const int bid  = blockIdx.x;
  const int slot = bid >> 2;
  const int gA   = bid & 3, gB = gA + 4;
  const int b0A  = gA * ROWS, b0B = gB * ROWS;
  const int lr = lane & 15, lg = lane >> 4;
  const int i0 = slot * 128 + wave * 32 + lr;   // col-set 0 neuron
  const int i1 = i0 + 16;                       // col-set 1 neuron

  // ---- persistent W fragments, both col-sets: B[k][col]=W[col][kb*32+k]*sign ----
  short8 wf0[32], wf1[32];
#pragma unroll
  for (int kb = 0; kb < 32; ++kb) {
    const int j0 = kb * 32 + lg * 8;
    f32x4 s0 = *(const f32x4*)(ds + j0);
    f32x4 s1 = *(const f32x4*)(ds + j0 + 4);
    const float* wp0 = W + (size_t)i0 * NN + j0;
    const float* wp1 = W + (size_t)i1 * NN + j0;
    f32x4 a = *(const f32x4*)(wp0), b = *(const f32x4*)(wp0 + 4);
    f32x4 c = *(const f32x4*)(wp1), d = *(const f32x4*)(wp1 + 4);
    short8 f, h;
    f[0]=(short)f2bf(a[0]*s0[0]); f[1]=(short)f2bf(a[1]*s0[1]);
    f[2]=(short)f2bf(a[2]*s0[2]); f[3]=(short)f2bf(a[3]*s0[3]);
    f[4]=(short)f2bf(b[0]*s1[0]); f[5]=(short)f2bf(b[1]*s1[1]);
    f[6]=(short)f2bf(b[2]*s1[2]); f[7]=(short)f2bf(b[3]*s1[3]);
    h[0]=(short)f2bf(c[0]*s0[0]); h[1]=(short)f2bf(c[1]*s0[1]);
    h[2]=(short)f2bf(c[2]*s0[2]); h[3]=(short)f2bf(c[3]*s0[3]);
    h[4]=(short)f2bf(d[0]*s1[0]); h[5]=(short)f2bf(d[1]*s1[1]);
    h[6]=(short)f2bf(d[2]*s1[2]); h[7]=(short)f2bf(d[3]*s1[3]);
    wf0[kb] = f; wf1[kb] = h;
  }
  short8 bin0, bin1;
#pragma unroll
  for (int e = 0; e < 8; ++e) {
    const int m = lg * 8 + e;
    bin0[e] = (short)f2bf(m < NIN ? Bm[(size_t)i0 * NIN + m] : 0.0f);
    bin1[e] = (short)f2bf(m < NIN ? Bm[(size_t)i1 * NIN + m] : 0.0f);
  }
  const float itau0 = 1.0f / tau[i0];
  const float itau1 = 1.0f / tau[i1];

  // ---- staging: whole block loads one 8-row tile (32 KB tagged u32) ----
  const int srow = tid >> 5;        // 0..7
  const int c32  = tid & 31;        // 0..31; lane covers 128B contiguous
  auto stage = [&](const unsigned* gt, unsigned tag, char* ldst) {
    const unsigned* gp = gt + srow * NN + c32 * 32;
    uint4v R0,R1,R2,R3,R4,R5,R6,R7;
    int guard = 0;
    for (;;) {
      asm volatile(
          "global_load_dwordx4 %0, %8, off sc0 sc1\n\t"
          "global_load_dwordx4 %1, %8, off offset:16 sc0 sc1\n\t"
          "global_load_dwordx4 %2, %8, off offset:32 sc0 sc1\n\t"
          "global_load_dwordx4 %3, %8, off offset:48 sc0 sc1\n\t"
          "global_load_dwordx4 %4, %8, off offset:64 sc0 sc1\n\t"
          "global_load_dwordx4 %5, %8, off offset:80 sc0 sc1\n\t"
          "global_load_dwordx4 %6, %8, off offset:96 sc0 sc1\n\t"
          "global_load_dwordx4 %7, %8, off offset:112 sc0 sc1\n\t"
          "s_waitcnt vmcnt(0)"
          : "=&v"(R0), "=&v"(R1), "=&v"(R2), "=&v"(R3),
            "=&v"(R4), "=&v"(R5), "=&v"(R6), "=&v"(R7)
          : "v"(gp) : "memory");
      unsigned bad = 0;
#define CK(Rx) bad |= ((Rx[0]>>16)^tag) | ((Rx[1]>>16)^tag) | \
                      ((Rx[2]>>16)^tag) | ((Rx[3]>>16)^tag)
      CK(R0); CK(R1); CK(R2); CK(R3); CK(R4); CK(R5); CK(R6); CK(R7);
#undef CK
      if (__all((int)(bad == 0))) break;
      if (++guard > RETRY_CAP) break;
    }
    char* wrow = ldst + srow * 2048;
    const int swz = srow << 4;
#define WR(Rx, j) *(unsigned long long*)(wrow + ((c32 * 64 + (j) * 8) ^ swz)) = \
    ((unsigned long long)(((Rx[2]&0xFFFFu)|(Rx[3]<<16))) << 32) | \
     (unsigned long long)(((Rx[0]&0xFFFFu)|(Rx[1]<<16)))
    WR(R0,0); WR(R1,1); WR(R2,2); WR(R3,3);
    WR(R4,4); WR(R5,5); WR(R6,6); WR(R7,7);
#undef WR
  };

  unsigned* par0 = obs32;
  unsigned* par1 = obs32 + PARSTRIDE;

  // ---- init r (both groups, both col-sets); publish tag 1 into parity 0 ----
  f32x4 rA0={0,0,0,0}, rA1={0,0,0,0}, rB0={0,0,0,0}, rB1={0,0,0,0};
  if (lg < 2) {
#pragma unroll
    for (int q = 0; q < 4; ++q) {
      const int row = lg * 4 + q;
      rA0[q] = r0[(size_t)(b0A + row) * NN + i0];
      rA1[q] = r0[(size_t)(b0A + row) * NN + i1];
      rB0[q] = r0[(size_t)(b0B + row) * NN + i0];
      rB1[q] = r0[(size_t)(b0B + row) * NN + i1];
      unsigned* tA = par0 + gA * (ROWS * NN) + row * NN;
      unsigned* tB = par0 + gB * (ROWS * NN) + row * NN;
      __hip_atomic_store(&tA[i0], (unsigned)f2bf(fmaxf(rA0[q],0.f)) | (1u<<16),
                         __ATOMIC_RELAXED, SCOPE_AGENT);
      __hip_atomic_store(&tA[i1], (unsigned)f2bf(fmaxf(rA1[q],0.f)) | (1u<<16),
                         __ATOMIC_RELAXED, SCOPE_AGENT);
      __hip_atomic_store(&tB[i0], (unsigned)f2bf(fmaxf(rB0[q],0.f)) | (1u<<16),
                         __ATOMIC_RELAXED, SCOPE_AGENT);
      __hip_atomic_store(&tB[i1], (unsigned)f2bf(fmaxf(rB1[q],0.f)) | (1u<<16),
                         __ATOMIC_RELAXED, SCOPE_AGENT);
    }
  }

  const float* ubA = u + (size_t)(b0A + lr) * NT * NIN;
  const float* ubB = u + (size_t)(b0B + lr) * NT * NIN;
  f32x4 uA0={0,0,0,0}, uA1={0,0,0,0}, uB0={0,0,0,0}, uB1={0,0,0,0};
  if (lr < 8 && lg < 3) {
    uA0 = *(const f32x4*)(ubA + lg * 8); uA1 = *(const f32x4*)(ubA + lg * 8 + 4);
    uB0 = *(const f32x4*)(ubB + lg * 8); uB1 = *(const f32x4*)(ubB + lg * 8 + 4);
  }

  const char* lrowA = lds + (lr & 7) * 2048;
  const char* lrowB = lrowA + ROWS * 2048;
  const int rswz = (lr & 7) << 4;

  for (int t = 0; t < NT; ++t) {
    const int par = t & 1;
    const unsigned tag  = (unsigned)(t + 1);
    const unsigned tag2 = (unsigned)(t + 2);
    unsigned* rd = par ? par1 : par0;
    unsigned* wr = par ? par0 : par1;

    // ================= phase A =================
    stage(rd + gA * (ROWS * NN), tag, lds);
    __syncthreads();
    {
      f32x4 a00={0,0,0,0}, a01={0,0,0,0}, a10={0,0,0,0}, a11={0,0,0,0};
      short8 ua;
      ua[0]=(short)f2bf(uA0[0]); ua[1]=(short)f2bf(uA0[1]);
      ua[2]=(short)f2bf(uA0[2]); ua[3]=(short)f2bf(uA0[3]);
      ua[4]=(short)f2bf(uA1[0]); ua[5]=(short)f2bf(uA1[1]);
      ua[6]=(short)f2bf(uA1[2]); ua[7]=(short)f2bf(uA1[3]);
      if (lr >= 8 || lg >= 3) ua = short8{0,0,0,0,0,0,0,0};
      a00 = MF(ua, bin0, a00); a10 = MF(ua, bin1, a10);
#pragma unroll
      for (int kb = 0; kb < 32; kb += 2) {
        short8 x = *(const short8*)(lrowA + ((kb * 64 + lg * 16) ^ rswz));
        short8 y = *(const short8*)(lrowA + (((kb+1) * 64 + lg * 16) ^ rswz));
        a00 = MF(x, wf0[kb],   a00); a10 = MF(x, wf1[kb],   a10);
        a01 = MF(y, wf0[kb+1], a01); a11 = MF(y, wf1[kb+1], a11);
      }
      if (lg < 2) {
        unsigned* gwA = wr + gA * (ROWS * NN);
#pragma unroll
        for (int q = 0; q < 4; ++q) {
          const int row = lg * 4 + q;
          float p0 = a00[q] + a01[q], p1 = a10[q] + a11[q];
          float act0 = 60.0f / (1.0f + expf(8.4f - 0.28f * p0));
          float act1 = 60.0f / (1.0f + expf(8.4f - 0.28f * p1));
          rA0[q] += (0.1f * (act0 - rA0[q])) * itau0;
          rA1[q] += (0.1f * (act1 - rA1[q])) * itau1;
          if (t != NT - 1) {
            __hip_atomic_store(&gwA[row * NN + i0],
                (unsigned)f2bf(fmaxf(rA0[q],0.f)) | (tag2<<16),
                __ATOMIC_RELAXED, SCOPE_AGENT);
            __hip_atomic_store(&gwA[row * NN + i1],
                (unsigned)f2bf(fmaxf(rA1[q],0.f)) | (tag2<<16),
                __ATOMIC_RELAXED, SCOPE_AGENT);
          }
          out[((size_t)(b0A + row) * NT + t) * NN + i0] = rA0[q];
          out[((size_t)(b0A + row) * NT + t) * NN + i1] = rA1[q];
        }
      }
      if (t != NT - 1 && lr < 8 && lg < 3) {
        const float* up = ubA + (t + 1) * NIN + lg * 8;
        uA0 = *(const f32x4*)(up); uA1 = *(const f32x4*)(up + 4);
      }
    }

    // ================= phase B =================
    stage(rd + gB * (ROWS * NN), tag, lds + ROWS * 2048);
    __syncthreads();
    {
      f32x4 a00={0,0,0,0}, a01={0,0,0,0}, a10={0,0,0,0}, a11={0,0,0,0};
      short8 ua;
      ua[0]=(short)f2bf(uB0[0]); ua[1]=(short)f2bf(uB0[1]);
      ua[2]=(short)f2bf(uB0[2]); ua[3]=(short)f2bf(uB0[3]);
      ua[4]=(short)f2bf(uB1[0]); ua[5]=(short)f2bf(uB1[1]);
      ua[6]=(short)f2bf(uB1[2]); ua[7]=(short)f2bf(uB1[3]);
      if (lr >= 8 || lg >= 3) ua = short8{0,0,0,0,0,0,0,0};
      a00 = MF(ua, bin0, a00); a10 = MF(ua, bin1, a10);
#pragma unroll
      for (int kb = 0; kb < 32; kb += 2) {
        short8 x = *(const short8*)(lrowB + ((kb * 64 + lg * 16) ^ rswz));
        short8 y = *(const short8*)(lrowB + (((kb+1) * 64 + lg * 16) ^ rswz));
        a00 = MF(x, wf0[kb],   a00); a10 = MF(x, wf1[kb],   a10);
        a01 = MF(y, wf0[kb+1], a01); a11 = MF(y, wf1[kb+1], a11);
      }
      if (lg < 2) {
        unsigned* gwB = wr + gB * (ROWS * NN);
#pragma unroll
        for (int q = 0; q < 4; ++q) {
          const int row = lg * 4 + q;
          float p0 = a00[q] + a01[q], p1 = a10[q] + a11[q];
          float act0 = 60.0f / (1.0f + expf(8.4f - 0.28f * p0));
          float act1 = 60.0f / (1.0f + expf(8.4f - 0.28f * p1));
          rB0[q] += (0.1f * (act0 - rB0[q])) * itau0;
          rB1[q] += (0.1f * (act1 - rB1[q])) * itau1;
          if (t != NT - 1) {
            __hip_atomic_store(&gwB[row * NN + i0],
                (unsigned)f2bf(fmaxf(rB0[q],0.f)) | (tag2<<16),
                __ATOMIC_RELAXED, SCOPE_AGENT);
            __hip_atomic_store(&gwB[row * NN + i1],
                (unsigned)f2bf(fmaxf(rB1[q],0.f)) | (tag2<<16),
                __ATOMIC_RELAXED, SCOPE_AGENT);
          }
          out[((size_t)(b0B + row) * NT + t) * NN + i0] = rB0[q];
          out[((size_t)(b0B + row) * NT + t) * NN + i1] = rB1[q];
        }
      }
      if (t != NT - 1 && lr < 8 && lg < 3) {
        const float* up = ubB + (t + 1) * NIN + lg * 8;
        uB0 = *(const f32x4*)(up); uB1 = *(const f32x4*)(up + 4);
      }
    }
  }

  // r_final (both groups, both col-sets)
  if (lg < 2) {
    const size_t fbase = (size_t)NBATCH * NT * NN;
#pragma unroll
    for (int q = 0; q < 4; ++q) {
      const int row = lg * 4 + q;
      out[fbase + (size_t)(b0A + row) * NN + i0] = rA0[q];
      out[fbase + (size_t)(b0A + row) * NN + i1] = rA1[q];
      out[fbase + (size_t)(b0B + row) * NN + i0] = rB0[q];
      out[fbase + (size_t)(b0B + row) * NN + i1] = rB1[q];
    }
  }
}

extern "C" void kernel_launch(void* const* d_in, const int* in_sizes, int n_in,
                              void* d_out, int out_size, void* d_ws, size_t ws_size,
                              hipStream_t stream) {
  const float* u   = (const float*)d_in[0];
  const float* r0  = (const float*)d_in[1];
  const float* W   = (const float*)d_in[2];
  const float* Bm  = (const float*)d_in[3];
  const float* tau = (const float*)d_in[4];
  const float* ds  = (const float*)d_in[5];
  float* out = (float*)d_out;

  unsigned* obs32 = (unsigned*)d_ws;

  // zero both epoch-tagged buffers every call (stale tags from a previous
  // replay would falsely validate -> must clear; 512 KB memset is ~0.1 us)
  hipMemsetAsync(d_ws, 0, 2 * PARSTRIDE * sizeof(unsigned), stream);

  rnn_step_all<<<dim3(32), dim3(256), 0, stream>>>(u, r0, W, Bm, tau, ds,
                                                   out, obs32);
}

// Round 16
// 2133.435 us; speedup vs baseline: 1.8519x; 1.8519x over previous
//
#include <hip/hip_runtime.h>

using short8 = __attribute__((ext_vector_type(8))) short;
using f32x4  = __attribute__((ext_vector_type(4))) float;
using uint4v = __attribute__((ext_vector_type(4))) unsigned;

#define NT     512
#define NBATCH 64
#define NN     1024
#define NIN    24
#define NG     4                      // groups of 16 batches
#define ROWS   16
#define TILE32 (ROWS * NN)            // u32 per group tile
#define PARSTRIDE (NG * TILE32)       // u32 per parity buffer (256 KB)
#define SCOPE_AGENT __HIP_MEMORY_SCOPE_AGENT
#define RETRY_CAP (1 << 17)           // fail loud (absmax), never hang

// ws: [0, 512KB) obs32: 2 parity buffers of {bf16 | epoch16<<16} words.
// Epoch-in-data sync (R13-proven). R15: K-split — each wave owns a K-slice
// (source-neuron slice) instead of a col-set: A-fragments come straight from
// global (tag-validated, read ONCE per block, no LDS staging), partial sums
// exchanged through a conflict-free LDS tile array. Same MFMA count.

__device__ __forceinline__ unsigned short f2bf(float x) {
  union { float f; unsigned u; } v; v.f = x;
  return (unsigned short)((v.u + 0x7FFFu + ((v.u >> 16) & 1u)) >> 16);
}
__device__ __forceinline__ f32x4 MF(short8 a, short8 b, f32x4 c) {
  return __builtin_amdgcn_mfma_f32_16x16x32_bf16(a, b, c, 0, 0, 0);
}

// pack two validated dwordx4 (8 tagged u32) into one bf16x8 fragment
#define PACKS8(dst, Rx, Ry) do { \
  union { unsigned u[4]; short8 s; } pk_; \
  pk_.u[0] = (Rx[0] & 0xFFFFu) | (Rx[1] << 16); \
  pk_.u[1] = (Rx[2] & 0xFFFFu) | (Rx[3] << 16); \
  pk_.u[2] = (Ry[0] & 0xFFFFu) | (Ry[1] << 16); \
  pk_.u[3] = (Ry[2] & 0xFFFFu) | (Ry[3] << 16); \
  dst = pk_.s; } while (0)

// 32 blocks x 512 thr (8 waves). Group g = bid&3 owns batches [16g,+16);
// slot = bid>>2 owns neurons [128*slot,+128). Wave w = K-slice [128w,+128)
// for the partial GEMM, and OWNS output col-set w (reduce + r-state + publish).
__global__ __launch_bounds__(512, 1) void rnn_step_all(
    const float* __restrict__ u, const float* __restrict__ r0,
    const float* __restrict__ W, const float* __restrict__ Bm,
    const float* __restrict__ tau, const float* __restrict__ ds,
    float* __restrict__ out, unsigned* __restrict__ obs32)
{
  __shared__ f32x4 pl[64][64];   // 64 KB: partial tile [c*8+w][lane], 16x16 f32

  const int tid  = threadIdx.x;
  const int wave = tid >> 6;
  const int lane = tid & 63;
  const int bid  = blockIdx.x;
  const int g    = bid & 3;
  const int slot = bid >> 2;
  const int b0   = g * ROWS;
  const int lr = lane & 15, lg = lane >> 4;
  const int i  = slot * 128 + wave * 16 + lr;   // OUTPUT neuron (col-set = wave)

  // ---- W fragments: ALL 8 col-sets x this wave's K-slice (128 VGPR) ----
  // wf[c][j][e] = W[slot*128+c*16+lr][wave*128 + j*32 + lg*8 + e] * sign
  short8 wf[8][4];
#pragma unroll
  for (int c = 0; c < 8; ++c) {
#pragma unroll
    for (int j = 0; j < 4; ++j) {
      const int col = slot * 128 + c * 16 + lr;
      const int k0  = wave * 128 + j * 32 + lg * 8;
      f32x4 w0 = *(const f32x4*)(W + (size_t)col * NN + k0);
      f32x4 w1 = *(const f32x4*)(W + (size_t)col * NN + k0 + 4);
      f32x4 s0 = *(const f32x4*)(ds + k0);
      f32x4 s1 = *(const f32x4*)(ds + k0 + 4);
      short8 f;
      f[0]=(short)f2bf(w0[0]*s0[0]); f[1]=(short)f2bf(w0[1]*s0[1]);
      f[2]=(short)f2bf(w0[2]*s0[2]); f[3]=(short)f2bf(w0[3]*s0[3]);
      f[4]=(short)f2bf(w1[0]*s1[0]); f[5]=(short)f2bf(w1[1]*s1[1]);
      f[6]=(short)f2bf(w1[2]*s1[2]); f[7]=(short)f2bf(w1[3]*s1[3]);
      wf[c][j] = f;
    }
  }
  short8 bin;
#pragma unroll
  for (int e = 0; e < 8; ++e) {
    const int m = lg * 8 + e;
    bin[e] = (short)f2bf(m < NIN ? Bm[(size_t)i * NIN + m] : 0.0f);
  }
  const float itau = 1.0f / tau[i];

  unsigned* gt0 = obs32 + g * TILE32;              // parity-0 tile
  unsigned* gt1 = obs32 + PARSTRIDE + g * TILE32;  // parity-1 tile

  // ---- init r (C/D: row=lg*4+q, col=lr); publish tag 1 into parity 0 ----
  f32x4 r;
#pragma unroll
  for (int q = 0; q < 4; ++q) {
    const int row = lg * 4 + q;
    r[q] = r0[(size_t)(b0 + row) * NN + i];
    __hip_atomic_store(&gt0[row * NN + i],
                       (unsigned)f2bf(fmaxf(r[q], 0.f)) | (1u << 16),
                       __ATOMIC_RELAXED, SCOPE_AGENT);
  }

  const float* ub = u + (size_t)(b0 + lr) * NT * NIN;
  f32x4 up0 = {0,0,0,0}, up1 = {0,0,0,0};
  if (lg < 3) {
    up0 = *(const f32x4*)(ub + lg * 8);
    up1 = *(const f32x4*)(ub + lg * 8 + 4);
  }

  for (int t = 0; t < NT; ++t) {
    const unsigned tag  = (unsigned)(t + 1);
    const unsigned tag2 = (unsigned)(t + 2);
    unsigned* rdt = (t & 1) ? gt1 : gt0;
    unsigned* wrt = (t & 1) ? gt0 : gt1;

    // ---- validated A load: rows=lr, k in this wave's slice (8 KB/wave) ----
    short8 af0, af1, af2, af3;
    {
      const unsigned* gp = rdt + lr * NN + wave * 128 + lg * 8;
      uint4v R0,R1,R2,R3,R4,R5,R6,R7;
      int guard = 0;
      for (;;) {
        asm volatile(
            "global_load_dwordx4 %0, %8, off sc0 sc1\n\t"
            "global_load_dwordx4 %1, %8, off offset:16 sc0 sc1\n\t"
            "global_load_dwordx4 %2, %8, off offset:128 sc0 sc1\n\t"
            "global_load_dwordx4 %3, %8, off offset:144 sc0 sc1\n\t"
            "global_load_dwordx4 %4, %8, off offset:256 sc0 sc1\n\t"
            "global_load_dwordx4 %5, %8, off offset:272 sc0 sc1\n\t"
            "global_load_dwordx4 %6, %8, off offset:384 sc0 sc1\n\t"
            "global_load_dwordx4 %7, %8, off offset:400 sc0 sc1\n\t"
            "s_waitcnt vmcnt(0)"
            : "=&v"(R0), "=&v"(R1), "=&v"(R2), "=&v"(R3),
              "=&v"(R4), "=&v"(R5), "=&v"(R6), "=&v"(R7)
            : "v"(gp) : "memory");
        unsigned bad = 0;
#define CK(Rx) bad |= ((Rx[0]>>16)^tag) | ((Rx[1]>>16)^tag) | \
                      ((Rx[2]>>16)^tag) | ((Rx[3]>>16)^tag)
        CK(R0); CK(R1); CK(R2); CK(R3); CK(R4); CK(R5); CK(R6); CK(R7);
#undef CK
        if (__all((int)(bad == 0))) break;
        if (++guard > RETRY_CAP) break;   // fail loud, never hang
      }
      PACKS8(af0, R0, R1); PACKS8(af1, R2, R3);
      PACKS8(af2, R4, R5); PACKS8(af3, R6, R7);
    }

    // ---- partial GEMM: 8 col-sets x 4 k-blocks (32 MFMA, static indices) ----
    f32x4 pacc[8];
#pragma unroll
    for (int c = 0; c < 8; ++c) {
      f32x4 p = {0,0,0,0};
      p = MF(af0, wf[c][0], p);
      p = MF(af1, wf[c][1], p);
      p = MF(af2, wf[c][2], p);
      p = MF(af3, wf[c][3], p);
      pacc[c] = p;
    }

    // ---- exchange partials (conflict-free: 16B-stride b128 writes/reads) ----
#pragma unroll
    for (int c = 0; c < 8; ++c)
      pl[c * 8 + wave][lane] = pacc[c];
    __syncthreads();

    f32x4 acc = pl[wave * 8 + 0][lane];
#pragma unroll
    for (int s = 1; s < 8; ++s)
      acc += pl[wave * 8 + s][lane];

    // ---- u-term folded in as one accumulate-MFMA (col-set = wave) ----
    short8 ua;
    ua[0]=(short)f2bf(up0[0]); ua[1]=(short)f2bf(up0[1]);
    ua[2]=(short)f2bf(up0[2]); ua[3]=(short)f2bf(up0[3]);
    ua[4]=(short)f2bf(up1[0]); ua[5]=(short)f2bf(up1[1]);
    ua[6]=(short)f2bf(up1[2]); ua[7]=(short)f2bf(up1[3]);
    if (lg >= 3) ua = short8{0,0,0,0,0,0,0,0};
    acc = MF(ua, bin, acc);

    // ---- state update ----
    f32x4 rv;
#pragma unroll
    for (int q = 0; q < 4; ++q) {
      const float act = 60.0f / (1.0f + expf(8.4f - 0.28f * acc[q]));
      rv[q] = r[q] + (0.1f * (act - r[q])) * itau;
      r[q]  = rv[q];
    }

    if (t != NT - 1) {
      // publish tagged obs (fire-and-forget agent stores)
#pragma unroll
      for (int q = 0; q < 4; ++q)
        __hip_atomic_store(&wrt[(lg * 4 + q) * NN + i],
                           (unsigned)f2bf(fmaxf(rv[q], 0.f)) | (tag2 << 16),
                           __ATOMIC_RELAXED, SCOPE_AGENT);
      // u prefetch for t+1
      if (lg < 3) {
        const float* up = ub + (t + 1) * NIN + lg * 8;
        up0 = *(const f32x4*)(up);
        up1 = *(const f32x4*)(up + 4);
      }
    }
#pragma unroll
    for (int q = 0; q < 4; ++q)
      out[((size_t)(b0 + lg * 4 + q) * NT + t) * NN + i] = rv[q];

    __syncthreads();   // LDS tiles reusable next step
  }

  // r_final
  const size_t fbase = (size_t)NBATCH * NT * NN;
#pragma unroll
  for (int q = 0; q < 4; ++q)
    out[fbase + (size_t)(b0 + lg * 4 + q) * NN + i] = r[q];
}

extern "C" void kernel_launch(void* const* d_in, const int* in_sizes, int n_in,
                              void* d_out, int out_size, void* d_ws, size_t ws_size,
                              hipStream_t stream) {
  const float* u   = (const float*)d_in[0];
  const float* r0  = (const float*)d_in[1];
  const float* W   = (const float*)d_in[2];
  const float* Bm  = (const float*)d_in[3];
  const float* tau = (const float*)d_in[4];
  const float* ds  = (const float*)d_in[5];
  float* out = (float*)d_out;

  unsigned* obs32 = (unsigned*)d_ws;

  // zero both epoch-tagged buffers every call (tags restart at 1 -> deterministic)
  hipMemsetAsync(d_ws, 0, 2 * PARSTRIDE * sizeof(unsigned), stream);

  rnn_step_all<<<dim3(32), dim3(512), 0, stream>>>(u, r0, W, Bm, tau, ds,
                                                   out, obs32);
}